// Round 3
// baseline (1105.102 us; speedup 1.0000x reference)
//
#include <hip/hip_runtime.h>
#include <hip/hip_bf16.h>
#include <math.h>

// Only rows (b, n==0) reach the output slice [:,0,-1,:] -> 4 independent
// sequences of 64 positions. One workgroup per sequence (1024 threads),
// NO grid barriers (agent fences cost ~80us each on gfx950 - R2 post-mortem).
// All cross-phase data flows through per-CU L1/L2 (coherent within a wg via
// __syncthreads) or LDS.

// Per-seq global workspace layout (float offsets from ws + s*SEQSTRIDE)
#define OFF_XC  0        // [64][256] conv input (x half of in_proj)
#define OFF_Z   16384    // [64][256] gate half
#define OFF_U   32768    // [64][256] post-conv activations
#define OFF_DT  49152    // [64][256] softplus dt
#define OFF_Y   65536    // [64][256] scan output
#define OFF_RES 81920    // [64][128] residual
#define SEQSTRIDE 98304

__device__ __forceinline__ float silu_f(float v) {
    return v / (1.0f + __expf(-v));
}
__device__ __forceinline__ float gelu_f(float v) {
    return 0.5f * v * (1.0f + erff(v * 0.70710678118654752f));
}

__global__ __launch_bounds__(1024) void fused_kernel(
    const float* __restrict__ mha_in, const int* __restrict__ mask,
    const float* __restrict__ mlp_w1, const float* __restrict__ mlp_b1,
    const float* __restrict__ mlp_w2, const float* __restrict__ mlp_b2,
    const float* __restrict__ in_proj_w,
    const float* __restrict__ conv_w, const float* __restrict__ conv_b,
    const float* __restrict__ x_proj_w,
    const float* __restrict__ dt_proj_w, const float* __restrict__ dt_proj_b,
    const float* __restrict__ A_log, const float* __restrict__ D_skip,
    const float* __restrict__ out_proj_w,
    const float* __restrict__ blk_norm_w, const float* __restrict__ norm_f_w,
    float* __restrict__ ws, float* __restrict__ out)
{
    const int s    = blockIdx.x;          // sequence 0..3
    const int tid  = threadIdx.x;         // 0..1023
    const int wave = tid >> 6;            // 0..15
    const int lane = tid & 63;
    const int half = lane >> 5;           // 0/1 within wave
    const int lrow = lane & 31;           // row within 32-row chunk
    const int hw   = wave * 2 + half;     // 0..31 half-wave id

    float* XC  = ws + (size_t)s * SEQSTRIDE + OFF_XC;
    float* Z   = ws + (size_t)s * SEQSTRIDE + OFF_Z;
    float* U   = ws + (size_t)s * SEQSTRIDE + OFF_U;
    float* DT  = ws + (size_t)s * SEQSTRIDE + OFF_DT;
    float* Y   = ws + (size_t)s * SEQSTRIDE + OFF_Y;
    float* RES = ws + (size_t)s * SEQSTRIDE + OFF_RES;

    // LDS: union region for matmul staging (max 33792 B) + small scratch
    __shared__ union {
        struct { float A[32][132]; float Bb[32][132]; } ab;  // 128-wide staging (pad->4-way)
        float W[32][260];                                     // 256-wide staging
    } mm;
    __shared__ float xdbl[64][48];      // x_proj output: dt-pre 0..7, B 8..23, C 24..39
    __shared__ float partLDS[16][32];
    __shared__ float scaleLDS[32];
    __shared__ float fing[256];
    __shared__ float finpart[4][128];
    __shared__ float validf;

    for (int layer = 0; layer < 4; ++layer) {
        // ================= phase A: two 32-row chunks ==========================
        for (int c = 0; c < 2; ++c) {
            const int r = c * 32 + lrow;       // row in sequence for matmul lanes
            float hv[8];                        // h values (valid on half==0)

            if (layer == 0) {
                // ---- load X chunk -> bufA ----
                {
                    int idx = tid * 4; int row = idx >> 7, col = idx & 127;
                    float4 xv = *(const float4*)&mha_in[(size_t)(s * 4096 + c * 32 + row) * 128 + col];
                    *(float4*)&mm.ab.A[row][col] = xv;
                }
                __syncthreads();
                // ---- MLP1: 8 cols/wave, K split by half (K=128 -> 16 quads each)
                {
                    int cb = wave * 8, k0 = half * 16;
                    float acc[8] = {};
                    for (int k4 = k0; k4 < k0 + 16; ++k4) {
                        float4 xv = *(const float4*)&mm.ab.A[lrow][k4 * 4];
                        #pragma unroll
                        for (int j = 0; j < 8; ++j) {
                            float4 w = *(const float4*)&mlp_w1[(size_t)(cb + j) * 128 + k4 * 4];
                            acc[j] += xv.x * w.x + xv.y * w.y + xv.z * w.z + xv.w * w.w;
                        }
                    }
                    #pragma unroll
                    for (int j = 0; j < 8; ++j) acc[j] += __shfl_xor(acc[j], 32);
                    if (half == 0) {
                        #pragma unroll
                        for (int j = 0; j < 8; ++j)
                            mm.ab.Bb[lrow][cb + j] = gelu_f(acc[j] + mlp_b1[cb + j]);
                    }
                }
                __syncthreads();
                // ---- MLP2 -> hv, residual = h2 ----
                {
                    int cb = wave * 8, k0 = half * 16;
                    float acc[8] = {};
                    for (int k4 = k0; k4 < k0 + 16; ++k4) {
                        float4 xv = *(const float4*)&mm.ab.Bb[lrow][k4 * 4];
                        #pragma unroll
                        for (int j = 0; j < 8; ++j) {
                            float4 w = *(const float4*)&mlp_w2[(size_t)(cb + j) * 128 + k4 * 4];
                            acc[j] += xv.x * w.x + xv.y * w.y + xv.z * w.z + xv.w * w.w;
                        }
                    }
                    #pragma unroll
                    for (int j = 0; j < 8; ++j) acc[j] += __shfl_xor(acc[j], 32);
                    if (half == 0) {
                        #pragma unroll
                        for (int j = 0; j < 8; ++j) {
                            hv[j] = acc[j] + mlp_b2[cb + j];
                            RES[(size_t)r * 128 + cb + j] = hv[j];
                        }
                    }
                }
            } else {
                // ---- gate: W = y * silu(z) (32 x 256) ----
                {
                    int idx = tid * 8; int row = idx >> 8, col = idx & 255;
                    int rg = c * 32 + row;
                    #pragma unroll
                    for (int q = 0; q < 2; ++q) {
                        float4 yv = *(const float4*)&Y[(size_t)rg * 256 + col + q * 4];
                        float4 zv = *(const float4*)&Z[(size_t)rg * 256 + col + q * 4];
                        float4 g;
                        g.x = yv.x * silu_f(zv.x); g.y = yv.y * silu_f(zv.y);
                        g.z = yv.z * silu_f(zv.z); g.w = yv.w * silu_f(zv.w);
                        *(float4*)&mm.W[row][col + q * 4] = g;
                    }
                }
                __syncthreads();
                // ---- out_proj: 8 cols/wave, K=256 split by half (32 quads each)
                {
                    const float* ow = out_proj_w + (size_t)(layer - 1) * 128 * 256;
                    int cb = wave * 8, k0 = half * 32;
                    float acc[8] = {};
                    for (int k4 = k0; k4 < k0 + 32; ++k4) {
                        float4 xv = *(const float4*)&mm.W[lrow][k4 * 4];
                        #pragma unroll
                        for (int j = 0; j < 8; ++j) {
                            float4 w = *(const float4*)&ow[(size_t)(cb + j) * 256 + k4 * 4];
                            acc[j] += xv.x * w.x + xv.y * w.y + xv.z * w.z + xv.w * w.w;
                        }
                    }
                    #pragma unroll
                    for (int j = 0; j < 8; ++j) acc[j] += __shfl_xor(acc[j], 32);
                    if (half == 0) {
                        #pragma unroll
                        for (int j = 0; j < 8; ++j) {
                            float v = acc[j] + RES[(size_t)r * 128 + cb + j];
                            hv[j] = v;
                            RES[(size_t)r * 128 + cb + j] = v;
                        }
                    }
                }
            }
            // ---- rmsnorm reduce over 128 cols ----
            {
                float p = 0.f;
                if (half == 0) {
                    #pragma unroll
                    for (int j = 0; j < 8; ++j) p += hv[j] * hv[j];
                }
                p += __shfl_xor(p, 32);
                __syncthreads();   // all matmul LDS reads done; partLDS free
                if (half == 0) partLDS[wave][lrow] = p;
                __syncthreads();
                if (tid < 32) {
                    float t = 0.f;
                    #pragma unroll
                    for (int w = 0; w < 16; ++w) t += partLDS[w][tid];
                    scaleLDS[tid] = rsqrtf(t * (1.0f / 128.0f) + 1e-5f);
                }
                __syncthreads();
            }
            // ---- hn -> bufA (aliases W; W is dead) ----
            {
                if (half == 0) {
                    int cb = wave * 8;
                    float sc = scaleLDS[lrow];
                    const float* bw = blk_norm_w + layer * 128;
                    #pragma unroll
                    for (int j = 0; j < 8; ++j)
                        mm.ab.A[lrow][cb + j] = hv[j] * sc * bw[cb + j];
                }
            }
            __syncthreads();
            // ---- in_proj: 16 cols per half-wave, K=128 -> XC, Z ----
            {
                const float* iw = in_proj_w + (size_t)layer * 512 * 128;
                int cb = hw * 16;
                float acc[16] = {};
                for (int k4 = 0; k4 < 32; ++k4) {
                    float4 xv = *(const float4*)&mm.ab.A[lrow][k4 * 4];
                    #pragma unroll
                    for (int g = 0; g < 4; ++g) {
                        #pragma unroll
                        for (int j = 0; j < 4; ++j) {
                            float4 w = *(const float4*)&iw[(size_t)(cb + g * 4 + j) * 128 + k4 * 4];
                            acc[g * 4 + j] += xv.x * w.x + xv.y * w.y + xv.z * w.z + xv.w * w.w;
                        }
                    }
                }
                #pragma unroll
                for (int g = 0; g < 4; ++g) {
                    float4 o;
                    o.x = acc[g * 4]; o.y = acc[g * 4 + 1]; o.z = acc[g * 4 + 2]; o.w = acc[g * 4 + 3];
                    int col = cb + g * 4;
                    if (col < 256) *(float4*)&XC[(size_t)r * 256 + col] = o;
                    else           *(float4*)&Z[(size_t)r * 256 + col - 256] = o;
                }
            }
            __syncthreads();
        } // chunks

        // ================= phase B: conv + x_proj + dt + scan =================
        // ---- causal conv (width 4) + silu: thread owns channel d, 16 rows ----
        {
            const int d = tid & 255;
            const int lbase = (tid >> 8) * 16;
            const float* cw = conv_w + (size_t)(layer * 256 + d) * 4;
            float w0 = cw[0], w1 = cw[1], w2 = cw[2], w3 = cw[3];
            float cb = conv_b[layer * 256 + d];
            float xm3 = (lbase - 3 >= 0) ? XC[(size_t)(lbase - 3) * 256 + d] : 0.f;
            float xm2 = (lbase - 2 >= 0) ? XC[(size_t)(lbase - 2) * 256 + d] : 0.f;
            float xm1 = (lbase - 1 >= 0) ? XC[(size_t)(lbase - 1) * 256 + d] : 0.f;
            for (int l = lbase; l < lbase + 16; ++l) {
                float x0 = XC[(size_t)l * 256 + d];
                float v = cb + w0 * xm3 + w1 * xm2 + w2 * xm1 + w3 * x0;
                U[(size_t)l * 256 + d] = silu_f(v);
                xm3 = xm2; xm2 = xm1; xm1 = x0;
            }
        }
        __syncthreads();
        // ---- x_proj: two 32-row chunks, u staged in LDS W ----
        {
            const float* xw = x_proj_w + (size_t)layer * 40 * 256;
            for (int c = 0; c < 2; ++c) {
                {
                    int idx = tid * 8; int row = idx >> 8, col = idx & 255;
                    float4 u0 = *(const float4*)&U[(size_t)(c * 32 + row) * 256 + col];
                    float4 u1 = *(const float4*)&U[(size_t)(c * 32 + row) * 256 + col + 4];
                    *(float4*)&mm.W[row][col] = u0;
                    *(float4*)&mm.W[row][col + 4] = u1;
                }
                __syncthreads();
                if (wave < 10) {
                    int cb = wave * 4, k0 = half * 32;
                    float acc[4] = {};
                    for (int k4 = k0; k4 < k0 + 32; ++k4) {
                        float4 xv = *(const float4*)&mm.W[lrow][k4 * 4];
                        #pragma unroll
                        for (int j = 0; j < 4; ++j) {
                            float4 w = *(const float4*)&xw[(size_t)(cb + j) * 256 + k4 * 4];
                            acc[j] += xv.x * w.x + xv.y * w.y + xv.z * w.z + xv.w * w.w;
                        }
                    }
                    #pragma unroll
                    for (int j = 0; j < 4; ++j) acc[j] += __shfl_xor(acc[j], 32);
                    if (half == 0) {
                        #pragma unroll
                        for (int j = 0; j < 4; ++j) xdbl[c * 32 + lrow][cb + j] = acc[j];
                    }
                }
                __syncthreads();
            }
        }
        // ---- dt = softplus(xdbl[:,:8] @ dtw^T + dtb) ----
        {
            const int d = tid & 255;
            const int lbase = (tid >> 8) * 16;
            const float* dw = dt_proj_w + (size_t)(layer * 256 + d) * 8;
            float w[8];
            #pragma unroll
            for (int t = 0; t < 8; ++t) w[t] = dw[t];
            float bdt = dt_proj_b[layer * 256 + d];
            for (int l = lbase; l < lbase + 16; ++l) {
                float pre = bdt;
                #pragma unroll
                for (int t = 0; t < 8; ++t) pre += xdbl[l][t] * w[t];
                DT[(size_t)l * 256 + d] = (pre > 20.f) ? pre : log1pf(__expf(pre));
            }
        }
        __syncthreads();
        // ---- selective scan: 4 threads per channel, 4 states each ----
        {
            const int d = tid >> 2, sub = tid & 3;
            float A[4], h[4] = {0.f, 0.f, 0.f, 0.f};
            #pragma unroll
            for (int j = 0; j < 4; ++j)
                A[j] = -__expf(A_log[(size_t)(layer * 256 + d) * 16 + sub * 4 + j]);
            float Dsk = D_skip[layer * 256 + d];

            float dtv = DT[d];
            float uv  = U[d];
            float4 B4 = *(const float4*)&xdbl[0][8 + sub * 4];
            float4 C4 = *(const float4*)&xdbl[0][24 + sub * 4];

            for (int l = 0; l < 64; ++l) {
                float dtn = 0.f, un = 0.f; float4 Bn = {0,0,0,0}, Cn = {0,0,0,0};
                if (l < 63) {
                    dtn = DT[(size_t)(l + 1) * 256 + d];
                    un  = U[(size_t)(l + 1) * 256 + d];
                    Bn  = *(const float4*)&xdbl[l + 1][8 + sub * 4];
                    Cn  = *(const float4*)&xdbl[l + 1][24 + sub * 4];
                }
                float du = dtv * uv;
                float yp = 0.f, dA;
                dA = __expf(dtv * A[0]); h[0] = dA * h[0] + du * B4.x; yp += h[0] * C4.x;
                dA = __expf(dtv * A[1]); h[1] = dA * h[1] + du * B4.y; yp += h[1] * C4.y;
                dA = __expf(dtv * A[2]); h[2] = dA * h[2] + du * B4.z; yp += h[2] * C4.z;
                dA = __expf(dtv * A[3]); h[3] = dA * h[3] + du * B4.w; yp += h[3] * C4.w;
                yp += __shfl_xor(yp, 1);
                yp += __shfl_xor(yp, 2);
                if (sub == 0) Y[(size_t)l * 256 + d] = yp + uv * Dsk;
                dtv = dtn; uv = un; B4 = Bn; C4 = Cn;
            }
        }
        __syncthreads();
    } // layers

    // ================= final epilogue: row l=63 only ==========================
    if (tid < 256) fing[tid] = Y[(size_t)63 * 256 + tid] * silu_f(Z[(size_t)63 * 256 + tid]);
    if (tid < 64) {
        unsigned long long b = __ballot(mask[s * 4096 + tid] != 0);
        if (tid == 0) validf = (b != 0ULL) ? 1.f : 0.f;
    }
    __syncthreads();
    if (tid < 512) {
        int j = tid & 127, kh = tid >> 7;
        const float* ow = out_proj_w + (size_t)3 * 128 * 256 + (size_t)j * 256;
        float acc = 0.f;
        for (int k4 = kh * 16; k4 < kh * 16 + 16; ++k4) {
            float4 g = *(const float4*)&fing[k4 * 4];
            float4 w = *(const float4*)&ow[k4 * 4];
            acc += g.x * w.x + g.y * w.y + g.z * w.z + g.w * w.w;
        }
        finpart[kh][j] = acc;
    }
    __syncthreads();
    float v = 0.f;
    if (tid < 128)
        v = finpart[0][tid] + finpart[1][tid] + finpart[2][tid] + finpart[3][tid]
          + RES[(size_t)63 * 128 + tid];
    float p = v * v;
    p += __shfl_xor(p, 1);  p += __shfl_xor(p, 2);  p += __shfl_xor(p, 4);
    p += __shfl_xor(p, 8);  p += __shfl_xor(p, 16); p += __shfl_xor(p, 32);
    if (lane == 0) partLDS[wave][0] = p;
    __syncthreads();
    if (tid < 128) {
        float tot = partLDS[0][0] + partLDS[1][0];
        out[s * 128 + tid] = v * rsqrtf(tot * (1.0f / 128.0f) + 1e-5f)
                           * norm_f_w[tid] * validf;
    }
}

// ---------------------------------------------------------------------------
extern "C" void kernel_launch(void* const* d_in, const int* in_sizes, int n_in,
                              void* d_out, int out_size, void* d_ws, size_t ws_size,
                              hipStream_t stream) {
    const float* mha_in     = (const float*)d_in[0];
    const int*   mask       = (const int*)  d_in[1];
    const float* mlp_w1     = (const float*)d_in[2];
    const float* mlp_b1     = (const float*)d_in[3];
    const float* mlp_w2     = (const float*)d_in[4];
    const float* mlp_b2     = (const float*)d_in[5];
    const float* in_proj_w  = (const float*)d_in[6];
    const float* conv_w     = (const float*)d_in[7];
    const float* conv_b     = (const float*)d_in[8];
    const float* x_proj_w   = (const float*)d_in[9];
    const float* dt_proj_w  = (const float*)d_in[10];
    const float* dt_proj_b  = (const float*)d_in[11];
    const float* A_log      = (const float*)d_in[12];
    const float* D_skip     = (const float*)d_in[13];
    const float* out_proj_w = (const float*)d_in[14];
    const float* blk_norm_w = (const float*)d_in[15];
    const float* norm_f_w   = (const float*)d_in[16];
    float* ws  = (float*)d_ws;
    float* out = (float*)d_out;

    fused_kernel<<<4, 1024, 0, stream>>>(mha_in, mask, mlp_w1, mlp_b1, mlp_w2, mlp_b2,
                                         in_proj_w, conv_w, conv_b, x_proj_w,
                                         dt_proj_w, dt_proj_b, A_log, D_skip,
                                         out_proj_w, blk_norm_w, norm_f_w, ws, out);
}

// Round 4
// 685.884 us; speedup vs baseline: 1.6112x; 1.6112x over previous
//
#include <hip/hip_runtime.h>
#include <hip/hip_bf16.h>
#include <math.h>

// Only rows (b, n==0) reach output slice [:,0,-1,:] -> 4 independent sequences
// of 64 positions. 8 launches: per layer K_A (32 wgs x 256: gate/MLP + residual
// + rmsnorm + in_proj, spread over 32 CUs) and K_BS (4 wgs x 1024: conv +
// x_proj + dt + scan fully LDS-resident). Kernel boundaries provide sync +
// coherence (grid barriers cost ~90us on gfx950 - R2; 4-CU matmuls starve - R3).

// Workspace layout (float offsets), 256 compact rows r = s*64 + l
#define WS_RESIDUAL 0          // [256][128]
#define WS_XZ       32768      // [256][512] cols 0..255 = xc, 256..511 = z
#define WS_Y        163840     // [256][256]

__device__ __forceinline__ float silu_f(float v) {
    return v / (1.0f + __expf(-v));
}

// ---------------------------------------------------------------------------
// K_A: [layer 0: full MLP] or [layer>0: gate + out_proj(prev)] + residual
//      + rmsnorm + in_proj.  32 wgs x 256 thr, 8 rows per wg.  (R1-proven)
// ---------------------------------------------------------------------------
__global__ __launch_bounds__(256) void ka_kernel(
    const float* __restrict__ mha_in,
    const float* __restrict__ mlp_w1, const float* __restrict__ mlp_b1,
    const float* __restrict__ mlp_w2, const float* __restrict__ mlp_b2,
    const float* __restrict__ in_proj_w, const float* __restrict__ out_proj_w,
    const float* __restrict__ blk_norm_w,
    float* __restrict__ ws, int layer)
{
    float* residual = ws + WS_RESIDUAL;
    float* xz       = ws + WS_XZ;
    float* ybuf     = ws + WS_Y;

    __shared__ float gated[8][256];   // layer0: cols 0..127 = x, 128..255 = h1
    __shared__ float res[8][128];
    __shared__ float hn[8][128];
    __shared__ float part[8][32];
    __shared__ float scale[8];

    const int tid  = threadIdx.x;
    const int row0 = blockIdx.x * 8;

    if (layer == 0) {
        for (int idx = tid; idx < 8*128; idx += 256) {
            int i = idx >> 7, c = idx & 127;
            int r = row0 + i; int s = r >> 6, l = r & 63;
            gated[i][c] = mha_in[(s*4096 + l)*128 + c];
        }
        __syncthreads();
        {   // h1 = gelu(x @ w1^T + b1)
            int jg = tid & 63, rq = tid >> 6;
            int j0 = jg*2;
            float acc[2][2] = {{0.f,0.f},{0.f,0.f}};
            for (int k4 = 0; k4 < 32; ++k4) {
                float4 w0 = *(const float4*)&mlp_w1[(j0  )*128 + k4*4];
                float4 w1 = *(const float4*)&mlp_w1[(j0+1)*128 + k4*4];
                #pragma unroll
                for (int rr = 0; rr < 2; ++rr) {
                    float4 xv = *(const float4*)&gated[rq*2+rr][k4*4];
                    acc[rr][0] += xv.x*w0.x + xv.y*w0.y + xv.z*w0.z + xv.w*w0.w;
                    acc[rr][1] += xv.x*w1.x + xv.y*w1.y + xv.z*w1.z + xv.w*w1.w;
                }
            }
            __syncthreads();
            #pragma unroll
            for (int rr = 0; rr < 2; ++rr)
                #pragma unroll
                for (int jj = 0; jj < 2; ++jj) {
                    float v = acc[rr][jj] + mlp_b1[j0+jj];
                    gated[rq*2+rr][128 + j0 + jj] = 0.5f*v*(1.0f + erff(v*0.70710678118f));
                }
        }
        __syncthreads();
        {   // h2 = h1 @ w2^T + b2
            int jg = tid & 63, rq = tid >> 6;
            int j0 = jg*2;
            float acc[2][2] = {{0.f,0.f},{0.f,0.f}};
            for (int k4 = 0; k4 < 32; ++k4) {
                float4 w0 = *(const float4*)&mlp_w2[(j0  )*128 + k4*4];
                float4 w1 = *(const float4*)&mlp_w2[(j0+1)*128 + k4*4];
                #pragma unroll
                for (int rr = 0; rr < 2; ++rr) {
                    float4 xv = *(const float4*)&gated[rq*2+rr][128 + k4*4];
                    acc[rr][0] += xv.x*w0.x + xv.y*w0.y + xv.z*w0.z + xv.w*w0.w;
                    acc[rr][1] += xv.x*w1.x + xv.y*w1.y + xv.z*w1.z + xv.w*w1.w;
                }
            }
            #pragma unroll
            for (int rr = 0; rr < 2; ++rr) {
                int i = rq*2 + rr, r = row0 + i;
                #pragma unroll
                for (int jj = 0; jj < 2; ++jj) {
                    float v = acc[rr][jj] + mlp_b2[j0+jj];
                    res[i][j0+jj] = v;
                    residual[r*128 + j0 + jj] = v;
                }
            }
        }
    } else {
        for (int idx = tid; idx < 8*256; idx += 256) {
            int i = idx >> 8, dd = idx & 255;
            int r = row0 + i;
            float yv = ybuf[r*256 + dd];
            float zv = xz[r*512 + 256 + dd];
            gated[i][dd] = yv * silu_f(zv);
        }
        __syncthreads();
        {
            const float* ow = out_proj_w + (size_t)(layer-1)*128*256;
            int jg = tid & 63, rq = tid >> 6;
            int j0 = jg*2;
            float acc[2][2] = {{0.f,0.f},{0.f,0.f}};
            for (int k4 = 0; k4 < 64; ++k4) {
                float4 w0 = *(const float4*)&ow[(j0  )*256 + k4*4];
                float4 w1 = *(const float4*)&ow[(j0+1)*256 + k4*4];
                #pragma unroll
                for (int rr = 0; rr < 2; ++rr) {
                    float4 xv = *(const float4*)&gated[rq*2+rr][k4*4];
                    acc[rr][0] += xv.x*w0.x + xv.y*w0.y + xv.z*w0.z + xv.w*w0.w;
                    acc[rr][1] += xv.x*w1.x + xv.y*w1.y + xv.z*w1.z + xv.w*w1.w;
                }
            }
            #pragma unroll
            for (int rr = 0; rr < 2; ++rr) {
                int i = rq*2 + rr, r = row0 + i;
                #pragma unroll
                for (int jj = 0; jj < 2; ++jj) {
                    float v = acc[rr][jj] + residual[r*128 + j0 + jj];
                    res[i][j0+jj] = v;
                    residual[r*128 + j0 + jj] = v;
                }
            }
        }
    }
    __syncthreads();

    // rmsnorm
    {
        int r = tid >> 5, lane = tid & 31;
        float sq = 0.f;
        #pragma unroll
        for (int t = 0; t < 4; ++t) { float v = res[r][lane + 32*t]; sq += v*v; }
        part[r][lane] = sq;
    }
    __syncthreads();
    if (tid < 8) {
        float sq = 0.f;
        #pragma unroll
        for (int t = 0; t < 32; ++t) sq += part[tid][t];
        scale[tid] = rsqrtf(sq * (1.0f/128.0f) + 1e-5f);
    }
    __syncthreads();
    {
        const float* bw = blk_norm_w + layer*128;
        for (int idx = tid; idx < 8*128; idx += 256) {
            int i = idx >> 7, c = idx & 127;
            hn[i][c] = res[i][c] * scale[i] * bw[c];
        }
    }
    __syncthreads();

    // xz = hn @ in_w^T  (8 x 512, K=128)
    {
        const float* iw = in_proj_w + (size_t)layer*512*128;
        int jg = tid & 127, rh = tid >> 7;
        int j0 = jg*4;
        float acc[4][4] = {};
        for (int k4 = 0; k4 < 32; ++k4) {
            float4 w[4];
            #pragma unroll
            for (int jj = 0; jj < 4; ++jj)
                w[jj] = *(const float4*)&iw[(j0+jj)*128 + k4*4];
            #pragma unroll
            for (int rr = 0; rr < 4; ++rr) {
                float4 xv = *(const float4*)&hn[rh*4+rr][k4*4];
                #pragma unroll
                for (int jj = 0; jj < 4; ++jj)
                    acc[rr][jj] += xv.x*w[jj].x + xv.y*w[jj].y + xv.z*w[jj].z + xv.w*w[jj].w;
            }
        }
        #pragma unroll
        for (int rr = 0; rr < 4; ++rr) {
            int r = row0 + rh*4 + rr;
            float4 o; o.x = acc[rr][0]; o.y = acc[rr][1]; o.z = acc[rr][2]; o.w = acc[rr][3];
            *(float4*)&xz[r*512 + j0] = o;
        }
    }
}

// ---------------------------------------------------------------------------
// K_BS: conv + silu + x_proj + dt + selective scan, all LDS-resident.
// 4 wgs x 1024 thr, one sequence each. do_fin: fold in final epilogue.
// ---------------------------------------------------------------------------
__global__ __launch_bounds__(1024) void kbs_kernel(
    const float* __restrict__ conv_w, const float* __restrict__ conv_b,
    const float* __restrict__ x_proj_w,
    const float* __restrict__ dt_proj_w, const float* __restrict__ dt_proj_b,
    const float* __restrict__ A_log, const float* __restrict__ D_skip,
    const float* __restrict__ out_proj_w, const float* __restrict__ norm_f_w,
    const int* __restrict__ mask,
    float* __restrict__ ws, float* __restrict__ out, int layer, int do_fin)
{
    // stride 260: conv write d-consecutive (32 banks), x_proj read row-broadcast,
    // scan read 8-addr broadcast -> conflict-free in all three patterns.
    __shared__ float uS[64][260];
    __shared__ float dtS[64][260];
    __shared__ float xdbl[64][48];    // 0..7 dt-pre, 8..23 B, 24..39 C
    __shared__ float fing[256];
    __shared__ float finpart[4][128];
    __shared__ float finred[2];
    __shared__ float validf;

    float* residual = ws + WS_RESIDUAL;
    float* xz       = ws + WS_XZ;
    float* ybuf     = ws + WS_Y;

    const int tid  = threadIdx.x;
    const int s    = blockIdx.x;
    const int base = s * 64;

    // ---- causal conv (width 4) + silu -> uS ----
    {
        const int d = tid & 255;
        const int lbase = (tid >> 8) * 16;
        const float* cw = conv_w + (size_t)(layer*256 + d)*4;
        float w0 = cw[0], w1 = cw[1], w2 = cw[2], w3 = cw[3];
        float cb = conv_b[layer*256 + d];
        float xm3 = (lbase >= 3) ? xz[(size_t)(base + lbase - 3)*512 + d] : 0.f;
        float xm2 = (lbase >= 2) ? xz[(size_t)(base + lbase - 2)*512 + d] : 0.f;
        float xm1 = (lbase >= 1) ? xz[(size_t)(base + lbase - 1)*512 + d] : 0.f;
        #pragma unroll
        for (int i = 0; i < 16; ++i) {
            int l = lbase + i;
            float x0 = xz[(size_t)(base + l)*512 + d];
            float v = cb + w0*xm3 + w1*xm2 + w2*xm1 + w3*x0;
            uS[l][d] = silu_f(v);
            xm3 = xm2; xm2 = xm1; xm1 = x0;
        }
    }
    __syncthreads();

    // ---- x_proj: 64 rows x 40 cols, K=256; row = tid>>4, 4 cols per thread ----
    {
        const float* xw = x_proj_w + (size_t)layer*40*256;
        int r = tid >> 4, t = tid & 15;
        if (t < 10) {
            int j0 = t*4;
            float acc[4] = {0.f,0.f,0.f,0.f};
            for (int k4 = 0; k4 < 64; ++k4) {
                float4 uv = *(const float4*)&uS[r][k4*4];
                #pragma unroll
                for (int j = 0; j < 4; ++j) {
                    float4 w = *(const float4*)&xw[(size_t)(j0+j)*256 + k4*4];
                    acc[j] += uv.x*w.x + uv.y*w.y + uv.z*w.z + uv.w*w.w;
                }
            }
            #pragma unroll
            for (int j = 0; j < 4; ++j) xdbl[r][j0+j] = acc[j];
        }
    }
    __syncthreads();

    // ---- dt = softplus(xdbl[:,:8] @ dtw^T + dtb) -> dtS ----
    {
        const int d = tid & 255;
        const int lbase = (tid >> 8) * 16;
        const float* dw = dt_proj_w + (size_t)(layer*256 + d)*8;
        float w[8];
        #pragma unroll
        for (int t = 0; t < 8; ++t) w[t] = dw[t];
        float bdt = dt_proj_b[layer*256 + d];
        #pragma unroll
        for (int i = 0; i < 16; ++i) {
            int l = lbase + i;
            float pre = bdt;
            #pragma unroll
            for (int t = 0; t < 8; ++t) pre += xdbl[l][t]*w[t];
            dtS[l][d] = (pre > 20.f) ? pre : log1pf(__expf(pre));
        }
    }
    __syncthreads();

    // ---- selective scan: 4 threads per channel, 4 states each, LDS operands --
    {
        const int d = tid >> 2, sub = tid & 3;
        float A[4], h[4] = {0.f,0.f,0.f,0.f};
        #pragma unroll
        for (int j = 0; j < 4; ++j)
            A[j] = -__expf(A_log[(size_t)(layer*256 + d)*16 + sub*4 + j]);
        float Dsk = D_skip[layer*256 + d];

        float dtv = dtS[0][d];
        float uv  = uS[0][d];
        float4 B4 = *(const float4*)&xdbl[0][ 8 + sub*4];
        float4 C4 = *(const float4*)&xdbl[0][24 + sub*4];

        for (int l = 0; l < 64; ++l) {
            float dtn = 0.f, un = 0.f; float4 Bn = {0,0,0,0}, Cn = {0,0,0,0};
            if (l < 63) {
                dtn = dtS[l+1][d];
                un  = uS[l+1][d];
                Bn  = *(const float4*)&xdbl[l+1][ 8 + sub*4];
                Cn  = *(const float4*)&xdbl[l+1][24 + sub*4];
            }
            float du = dtv * uv;
            float yp = 0.f, dA;
            dA = __expf(dtv*A[0]); h[0] = dA*h[0] + du*B4.x; yp += h[0]*C4.x;
            dA = __expf(dtv*A[1]); h[1] = dA*h[1] + du*B4.y; yp += h[1]*C4.y;
            dA = __expf(dtv*A[2]); h[2] = dA*h[2] + du*B4.z; yp += h[2]*C4.z;
            dA = __expf(dtv*A[3]); h[3] = dA*h[3] + du*B4.w; yp += h[3]*C4.w;
            yp += __shfl_xor(yp, 1);
            yp += __shfl_xor(yp, 2);
            if (sub == 0) ybuf[(size_t)(base + l)*256 + d] = yp + uv*Dsk;
            dtv = dtn; uv = un; B4 = Bn; C4 = Cn;
        }
    }

    if (!do_fin) return;

    // ================= final epilogue: row l=63 only ==========================
    __syncthreads();   // drain ybuf writes (visible within wg)
    if (tid < 256)
        fing[tid] = ybuf[(size_t)(base + 63)*256 + tid]
                  * silu_f(xz[(size_t)(base + 63)*512 + 256 + tid]);
    if (tid < 64) {
        unsigned long long b = __ballot(mask[s*4096 + tid] != 0);
        if (tid == 0) validf = (b != 0ULL) ? 1.f : 0.f;
    }
    __syncthreads();
    if (tid < 512) {
        int j = tid & 127, kh = tid >> 7;
        const float* ow = out_proj_w + (size_t)3*128*256 + (size_t)j*256;
        float acc = 0.f;
        for (int k4 = kh*16; k4 < kh*16 + 16; ++k4) {
            float4 g = *(const float4*)&fing[k4*4];
            float4 w = *(const float4*)&ow[k4*4];
            acc += g.x*w.x + g.y*w.y + g.z*w.z + g.w*w.w;
        }
        finpart[kh][j] = acc;
    }
    __syncthreads();
    float v = 0.f;
    if (tid < 128)
        v = finpart[0][tid] + finpart[1][tid] + finpart[2][tid] + finpart[3][tid]
          + residual[(size_t)(base + 63)*128 + tid];
    float p = v * v;
    p += __shfl_xor(p, 1);  p += __shfl_xor(p, 2);  p += __shfl_xor(p, 4);
    p += __shfl_xor(p, 8);  p += __shfl_xor(p, 16); p += __shfl_xor(p, 32);
    if (tid < 128 && (tid & 63) == 0) finred[tid >> 6] = p;
    __syncthreads();
    if (tid < 128) {
        float tot = finred[0] + finred[1];
        out[s*128 + tid] = v * rsqrtf(tot * (1.0f/128.0f) + 1e-5f)
                         * norm_f_w[tid] * validf;
    }
}

// ---------------------------------------------------------------------------
extern "C" void kernel_launch(void* const* d_in, const int* in_sizes, int n_in,
                              void* d_out, int out_size, void* d_ws, size_t ws_size,
                              hipStream_t stream) {
    const float* mha_in     = (const float*)d_in[0];
    const int*   mask       = (const int*)  d_in[1];
    const float* mlp_w1     = (const float*)d_in[2];
    const float* mlp_b1     = (const float*)d_in[3];
    const float* mlp_w2     = (const float*)d_in[4];
    const float* mlp_b2     = (const float*)d_in[5];
    const float* in_proj_w  = (const float*)d_in[6];
    const float* conv_w     = (const float*)d_in[7];
    const float* conv_b     = (const float*)d_in[8];
    const float* x_proj_w   = (const float*)d_in[9];
    const float* dt_proj_w  = (const float*)d_in[10];
    const float* dt_proj_b  = (const float*)d_in[11];
    const float* A_log      = (const float*)d_in[12];
    const float* D_skip     = (const float*)d_in[13];
    const float* out_proj_w = (const float*)d_in[14];
    const float* blk_norm_w = (const float*)d_in[15];
    const float* norm_f_w   = (const float*)d_in[16];
    float* ws  = (float*)d_ws;
    float* out = (float*)d_out;

    for (int layer = 0; layer < 4; ++layer) {
        ka_kernel<<<32, 256, 0, stream>>>(mha_in, mlp_w1, mlp_b1, mlp_w2, mlp_b2,
                                          in_proj_w, out_proj_w, blk_norm_w, ws, layer);
        kbs_kernel<<<4, 1024, 0, stream>>>(conv_w, conv_b, x_proj_w,
                                           dt_proj_w, dt_proj_b, A_log, D_skip,
                                           out_proj_w, norm_f_w, mask,
                                           ws, out, layer, (layer == 3) ? 1 : 0);
    }
}